// Round 14
// baseline (186.562 us; speedup 1.0000x reference)
//
#include <hip/hip_runtime.h>
#include <stdint.h>

typedef __bf16 bf16;
typedef bf16 bf16x2 __attribute__((ext_vector_type(2)));
typedef bf16 bf16x4 __attribute__((ext_vector_type(4)));
typedef bf16 bf16x8 __attribute__((ext_vector_type(8)));
typedef float f32x4 __attribute__((ext_vector_type(4)));
typedef float f32x16 __attribute__((ext_vector_type(16)));

static constexpr int Bc = 4, Sc = 1024, Ec = 1024, Hc = 16, Dc = 64, BSc = 4096;

__device__ __forceinline__ void gld_lds16(const void* g, void* s) {
  __builtin_amdgcn_global_load_lds((const __attribute__((address_space(1))) void*)g,
                                   (__attribute__((address_space(3))) void*)s, 16, 0, 0);
}

// ---------------------------------------------------------------------------
// Fused prep: blocks [0,2048) convert q/k/v fp32->bf16; [2048,3072) scan the
// mask (stride detected locally; mflag[0]=anyFalse via atomicOr, mflag[1]=
// stride); [3072,4096) transpose+convert the 4 weight matrices.
__global__ __launch_bounds__(256) void prep_kernel(
    const float* __restrict__ q, const float* __restrict__ k, const float* __restrict__ v,
    bf16* __restrict__ xb, const uint8_t* __restrict__ mask, int* __restrict__ mflag,
    const float* __restrict__ Wq, const float* __restrict__ Wk,
    const float* __restrict__ Wv, const float* __restrict__ Wo, bf16* __restrict__ wT) {
  __shared__ float tile[64][65];
  const int bid = blockIdx.x, t = threadIdx.x;

  if (bid < 2048) {
    // ---- convert_x
    const int n4 = (BSc * Ec) / 4;
    for (int i = bid * 256 + t; i < 3 * n4; i += 2048 * 256) {
      int which = i / n4;
      int off = i - which * n4;
      const float4* src = (which == 0) ? (const float4*)q : (which == 1) ? (const float4*)k : (const float4*)v;
      float4 f = src[off];
      bf16x4 o;
      o[0] = (bf16)f.x; o[1] = (bf16)f.y; o[2] = (bf16)f.z; o[3] = (bf16)f.w;
      *(bf16x4*)(xb + (size_t)which * BSc * Ec + (size_t)off * 4) = o;
    }
  } else if (bid < 3072) {
    // ---- scan_mask (local stride detection from first 64 bytes)
    bool everyGroupHasZero = true, anyNonzero = false;
    for (int j = 0; j < 16; ++j) {
      bool z = false;
      for (int bjj = 0; bjj < 4; ++bjj) {
        uint8_t byte = mask[4 * j + bjj];
        if (byte == 0) z = true;
        if (byte != 0) anyNonzero = true;
      }
      if (!z) everyGroupHasZero = false;
    }
    const int stride = (everyGroupHasZero && anyNonzero) ? 4 : 1;
    if (t == 0) mflag[1] = stride;  // same value from every scan block
    bool ok = true;
    const uint4* p = (const uint4*)mask;
    const int sb = bid - 2048;
    if (stride == 1) {
      const int n = (Bc * Sc * Sc) / 16;
      for (int i = sb * 256 + t; i < n; i += 1024 * 256) {
        uint4 w = p[i];
        uint32_t z = 0;
        z |= (w.x - 0x01010101u) & ~w.x;
        z |= (w.y - 0x01010101u) & ~w.y;
        z |= (w.z - 0x01010101u) & ~w.z;
        z |= (w.w - 0x01010101u) & ~w.w;
        if (z & 0x80808080u) ok = false;
      }
    } else {
      const int n = (Bc * Sc * Sc) / 4;
      for (int i = sb * 256 + t; i < n; i += 1024 * 256) {
        uint4 w = p[i];
        if (w.x == 0u || w.y == 0u || w.z == 0u || w.w == 0u) ok = false;
      }
    }
    if (!ok) atomicOr(&mflag[0], 1);  // anyFalse
  } else {
    // ---- convtrans_w: W [K][N] fp32 -> WT [N][K] bf16
    const int i = bid - 3072;
    const int z = i >> 8, rem = i & 255;
    const int k0 = (rem & 15) * 64, n0 = (rem >> 4) * 64;
    const float* W = (z == 0) ? Wq : (z == 1) ? Wk : (z == 2) ? Wv : Wo;
    bf16* out = wT + (size_t)z * Ec * Ec;
#pragma unroll
    for (int p2 = 0; p2 < 16; p2++) {
      int r = p2 * 4 + (t >> 6), c = t & 63;
      tile[r][c] = W[(size_t)(k0 + r) * Ec + n0 + c];
    }
    __syncthreads();
#pragma unroll
    for (int p2 = 0; p2 < 8; p2++) {
      int n = p2 * 8 + (t >> 5), kk = (t & 31) * 2;
      bf16x2 v2;
      v2[0] = (bf16)tile[kk][n];
      v2[1] = (bf16)tile[kk + 1][n];
      *(bf16x2*)(out + (size_t)(n0 + n) * Ec + k0 + kk) = v2;
    }
  }
}

// ---------------------------------------------------------------------------
// 128x128-tile bf16 GEMM. MODE 0: fp32 [M][N] out. MODE 1: bf16 head-split
// [B,H,S,D] out; z==0 (Q) pre-scaled by 0.125; z==1 (K) stored with the attn
// LDS swizzle pre-applied: d' = d ^ ((s&7)<<3). z==2 (V): writes VTb [bh][D][S]
// directly (transposed through LDS, attn s-swizzle pre-applied).
template <int MODE>
__global__ __launch_bounds__(256) void gemm128_kernel(
    const bf16* __restrict__ A_, const bf16* __restrict__ W_,
    const float* __restrict__ bias0, const float* __restrict__ bias1, const float* __restrict__ bias2,
    bf16* __restrict__ outb_, float* __restrict__ outf, bf16* __restrict__ VTb) {
  constexpr int K = 1024, N = 1024;
  const int z = blockIdx.z;
  const bf16* A = A_ + (size_t)z * BSc * K;
  const bf16* Wt = W_ + (size_t)z * N * K;
  const float* bias = (z == 0) ? bias0 : (z == 1) ? bias1 : bias2;
  bf16* outb = outb_ + (size_t)z * Bc * Hc * Sc * Dc;
  const float oscale = (MODE == 1 && z == 0) ? 0.125f : 1.0f;
  const int n0 = blockIdx.x * 128, m0 = blockIdx.y * 128;

  __shared__ __attribute__((aligned(16))) char gsm[32768];
  bf16* As = (bf16*)gsm;
  bf16* Bs = (bf16*)(gsm + 16384);
  const int t = threadIdx.x, wave = t >> 6, lane = t & 63;
  const int wr = wave >> 1, wc = wave & 1;

  f32x4 acc[4][4];
#pragma unroll
  for (int i = 0; i < 4; i++)
#pragma unroll
    for (int j = 0; j < 4; j++)
#pragma unroll
      for (int r = 0; r < 4; r++) acc[i][j][r] = 0.f;

  const int srow = (lane >> 3);
  const int scol = (lane & 7) * 8;

  for (int kt = 0; kt < K; kt += 64) {
#pragma unroll
    for (int i = 0; i < 4; i++) {
      const int chunk = i * 4 + wave;
      const int row = chunk * 8 + srow;
      gld_lds16(A + (size_t)(m0 + row) * K + kt + scol, &As[chunk * 512]);
      gld_lds16(Wt + (size_t)(n0 + row) * K + kt + scol, &Bs[chunk * 512]);
    }
    __syncthreads();
#pragma unroll
    for (int kk = 0; kk < 2; kk++) {
      bf16x8 af[4], bg[4];
#pragma unroll
      for (int i = 0; i < 4; i++) {
        af[i] = *(const bf16x8*)&As[(64 * wr + i * 16 + (lane & 15)) * 64 + kk * 32 + (lane >> 4) * 8];
        bg[i] = *(const bf16x8*)&Bs[(64 * wc + i * 16 + (lane & 15)) * 64 + kk * 32 + (lane >> 4) * 8];
      }
#pragma unroll
      for (int mi = 0; mi < 4; mi++)
#pragma unroll
        for (int ni = 0; ni < 4; ni++)
          acc[mi][ni] = __builtin_amdgcn_mfma_f32_16x16x32_bf16(af[mi], bg[ni], acc[mi][ni], 0, 0, 0);
    }
    __syncthreads();
  }

  if (MODE == 1 && z == 2) {
    // ---- fused VT epilogue: per-wave [32 d][72 s] LDS transpose, 2 halves.
    bf16* vtw = (bf16*)gsm + wave * 2304;
    const int head = (n0 >> 6) + wc;
    const int bidx = (m0 + 64 * wr) >> 10;
    const int sbase = (m0 + 64 * wr) & 1023;
    bf16* vbase = VTb + ((size_t)(bidx * Hc + head) * Dc) * Sc;
#pragma unroll
    for (int h2 = 0; h2 < 2; h2++) {
      __syncthreads();
#pragma unroll
      for (int mi = 0; mi < 4; mi++) {
#pragma unroll
        for (int ni2 = 0; ni2 < 2; ni2++) {
          const int ni = h2 * 2 + ni2;
          const float bvl = bias[n0 + 64 * wc + ni * 16 + (lane & 15)];
          const int dl = ni2 * 16 + (lane & 15);
#pragma unroll
          for (int rp = 0; rp < 2; rp++) {
            bf16x2 v2;
            v2[0] = (bf16)(acc[mi][ni][rp * 2] + bvl);
            v2[1] = (bf16)(acc[mi][ni][rp * 2 + 1] + bvl);
            *(bf16x2*)&vtw[dl * 72 + mi * 16 + (lane >> 4) * 4 + rp * 2] = v2;
          }
        }
      }
      __syncthreads();
#pragma unroll
      for (int i2 = 0; i2 < 4; i2++) {
        const int dl = i2 * 8 + (lane >> 3);
        const int d = h2 * 32 + dl;
        const int cp = lane & 7;
        const int cs = cp ^ (d & 7);
        const bf16x8 vv = *(const bf16x8*)&vtw[dl * 72 + cs * 8];
        *(bf16x8*)(vbase + (size_t)d * Sc + sbase + cp * 8) = vv;
      }
    }
    return;
  }

#pragma unroll
  for (int mi = 0; mi < 4; mi++) {
#pragma unroll
    for (int ni = 0; ni < 4; ni++) {
      const int col = n0 + 64 * wc + ni * 16 + (lane & 15);
      const float bvl = bias[col];
#pragma unroll
      for (int r = 0; r < 4; r++) {
        const int row = m0 + 64 * wr + mi * 16 + (lane >> 4) * 4 + r;
        const float v = (acc[mi][ni][r] + bvl) * oscale;
        if (MODE == 0) {
          outf[(size_t)row * N + col] = v;
        } else {
          const int bidx = row >> 10, s = row & 1023, hh = col >> 6, d = col & 63;
          const int dst = (z == 1) ? (d ^ ((s & 7) << 3)) : d;  // K pre-swizzle
          outb[(((size_t)bidx * Hc + hh) * Sc + s) * Dc + dst] = (bf16)v;
        }
      }
    }
  }
}

// ---------------------------------------------------------------------------
// QK 32k x 32q score tile from swizzled LDS K tile (rows of 128B,
// byte ^= ((row&7)<<4)). Lane = q column; rows (reg&3)+8*(reg>>2)+4*hi.
__device__ __forceinline__ f32x16 qk_lds(const char* sK, const bf16x8 qf[4],
                                         int koff, int l31, int hi) {
  const int row = koff + l31;
  const char* base = sK + row * 128;
  const int sw = (row & 7) << 4;
  f32x16 a;
#pragma unroll
  for (int r = 0; r < 16; r++) a[r] = 0.f;
#pragma unroll
  for (int ks = 0; ks < 4; ks++) {
    const bf16x8 kf = *(const bf16x8*)(base + ((ks * 32 + hi * 16) ^ sw));
    a = __builtin_amdgcn_mfma_f32_32x32x16_bf16(kf, qf[ks], a, 0, 0, 0);
  }
  return a;
}

__device__ __forceinline__ void mask_app(f32x16& a, int kt, const uint8_t* mrow1,
                                         const uint8_t* mrow4, int mstride, int hi) {
  if (mstride == 1) {
#pragma unroll
    for (int gg = 0; gg < 4; gg++) {
      const int kg = kt + gg * 8 + hi * 4;
      const uint32_t mw = *(const uint32_t*)(mrow1 + kg);
#pragma unroll
      for (int r = 0; r < 4; r++)
        if (((mw >> (8 * r)) & 0xffu) == 0u) a[gg * 4 + r] = -1e9f;
    }
  } else {
#pragma unroll
    for (int gg = 0; gg < 4; gg++) {
      const int kg = kt + gg * 8 + hi * 4;
      const uint4 m4 = *(const uint4*)(mrow4 + (size_t)4 * kg);
      const uint32_t w[4] = {m4.x, m4.y, m4.z, m4.w};
#pragma unroll
      for (int r = 0; r < 4; r++)
        if (w[r] == 0u) a[gg * 4 + r] = -1e9f;
    }
  }
}

// ---------------------------------------------------------------------------
// Fused attention v11. Round-14 changes:
//  (1) pass 1 k-step 128 (K-only dbuf 2x16KB in the same 32KB region):
//      8 barriers instead of 16 — halves the exposed vmcnt(0) drains.
//  (2) XCD-aware 1D grid swizzle: swz=(lin&7)*64+(lin>>3) (bijective) puts
//      all 8 qg-WGs of one (b,h) on the same XCD -> K/V head L2-resident
//      (8 heads x 256KB = 2MB per XCD L2).
// Pass 2 unchanged (64-k K+V dbuf, bf16 Ptb, dense 128B weight stores).
__global__ __launch_bounds__(256, 3) void attn_kernel(
    const bf16* __restrict__ Qb, const bf16* __restrict__ Kb, const bf16* __restrict__ VTb,
    const uint8_t* __restrict__ mask, const int* __restrict__ mflag,
    float* __restrict__ wout_, bf16* __restrict__ ctx) {
  const int lin = blockIdx.x;
  const int swz = (lin & 7) * 64 + (lin >> 3);
  const int qg = swz & 7, hb = swz >> 3;
  const int h = hb & 15, b = hb >> 4;
  const int bh = b * Hc + h;
  const int t = threadIdx.x, wave = t >> 6, lane = t & 63;
  const int l31 = lane & 31, hi = lane >> 5;
  const int q0 = qg * 128 + wave * 32;
  const int q = q0 + l31;

  // pass 1: [0,32K) = K dbuf (2 x [128 k][64 d] bf16, rows swizzled)
  // pass 2: [0,16K) K dbuf (2 x 8K), [16K,32K) VT dbuf (2 x 8K)
  // [32K,42K): Ptb, 4 waves x bf16[32][40] (wave-private)
  __shared__ __attribute__((aligned(16))) char smem[43008];
  bf16* Ptb = (bf16*)(smem + 32768) + wave * 1280;

  const bf16* Qp = Qb + ((size_t)bh * Sc + q) * Dc;
  bf16x8 qf[4];
#pragma unroll
  for (int ks = 0; ks < 4; ks++) qf[ks] = *(const bf16x8*)(Qp + ks * 16 + hi * 8);

  const int allTrue = !mflag[0];
  const int mstride = mflag[1];
  const uint8_t* mrow1 = mask + (size_t)(b * Sc + q) * Sc;
  const uint8_t* mrow4 = mask + (size_t)(b * Sc + q) * Sc * 4;

  const char* Kbb = (const char*)(Kb + (size_t)bh * Sc * Dc);
  const char* VTbb = (const char*)(VTb + (size_t)bh * Dc * Sc);

  // ==== pass 1: L = sum_k exp(s) per q-row (M=0), 128-k K-only dbuf stages
  float l = 0.f;
#pragma unroll
  for (int j = 0; j < 4; j++) {  // prologue: stage 0 -> Kbuf0 (16 KB)
    const int off = j * 4096 + wave * 1024;
    gld_lds16(Kbb + off + lane * 16, smem + off);
  }
  __syncthreads();
  for (int st = 0; st < 8; st++) {
    const int cur = st & 1;
    if (st < 7) {  // issue next 16KB stage into Kbuf^1 BEFORE compute
#pragma unroll
      for (int j = 0; j < 4; j++) {
        const int off = j * 4096 + wave * 1024;
        gld_lds16(Kbb + (st + 1) * 16384 + off + lane * 16,
                  smem + (cur ^ 1) * 16384 + off);
      }
    }
    const char* sK = smem + cur * 16384;
#pragma unroll
    for (int tl = 0; tl < 4; tl++) {
      f32x16 a = qk_lds(sK, qf, tl * 32, l31, hi);
      if (!allTrue) mask_app(a, st * 128 + tl * 32, mrow1, mrow4, mstride, hi);
      float s = 0.f;
#pragma unroll
      for (int r = 0; r < 16; r++) s += __expf(a[r]);
      l += s;
    }
    __syncthreads();  // next buffer filled + cur reads done
  }
  l += __shfl_xor(l, 32);  // combine the two 16-k halves (lanes l, l+32)
  const float invl = 1.f / l;

  // ==== pass 2: QK -> P = exp(a)*invl (bf16 Ptb) -> dense stores + PV
  float* wbase = wout_ + ((size_t)bh * Sc + q0) * Sc;
  f32x16 oacc[2];
#pragma unroll
  for (int nj = 0; nj < 2; nj++)
#pragma unroll
    for (int r = 0; r < 16; r++) oacc[nj][r] = 0.f;

  __syncthreads();  // pass-1 buffer reads fully done before re-purposing smem
#pragma unroll
  for (int j = 0; j < 2; j++) {  // prologue: stage 0 (K + V) -> buf0
    const int off = j * 4096 + wave * 1024;
    gld_lds16(Kbb + off + lane * 16, smem + off);
    const int goff = off + lane * 16;
    const int d = goff >> 7, ko = goff & 127;  // sV [64 d][128B k-slice]
    gld_lds16(VTbb + (size_t)d * 2048 + ko, smem + 16384 + off);
  }
  __syncthreads();
  for (int st = 0; st < 16; st++) {
    const int cur = st & 1;
    if (st < 15) {  // issue next K + V stage into buf^1 BEFORE compute
#pragma unroll
      for (int j = 0; j < 2; j++) {
        const int off = j * 4096 + wave * 1024;
        gld_lds16(Kbb + (st + 1) * 8192 + off + lane * 16, smem + (cur ^ 1) * 8192 + off);
        const int goff = off + lane * 16;
        const int d = goff >> 7, ko = goff & 127;
        gld_lds16(VTbb + (size_t)d * 2048 + (st + 1) * 128 + ko,
                  smem + 16384 + (cur ^ 1) * 8192 + off);
      }
    }
    const char* sK = smem + cur * 8192;
    const char* sV = smem + 16384 + cur * 8192;
#pragma unroll
    for (int tl = 0; tl < 2; tl++) {
      f32x16 a = qk_lds(sK, qf, tl * 32, l31, hi);
      if (!allTrue) mask_app(a, st * 64 + tl * 32, mrow1, mrow4, mstride, hi);
      // P = exp(a)*invl -> Ptb bf16 (klocal(reg) = (reg&3)+8*(reg>>2)+4*hi)
#pragma unroll
      for (int gg = 0; gg < 4; gg++) {
        bf16x4 p4;
#pragma unroll
        for (int r = 0; r < 4; r++) p4[r] = (bf16)(__expf(a[gg * 4 + r]) * invl);
        *(bf16x4*)&Ptb[l31 * 40 + gg * 8 + hi * 4] = p4;
      }
      // dense weight stores: 4 instrs x (8 rows x 128B full lines), nontemporal
#pragma unroll
      for (int i = 0; i < 4; i++) {
        const int q2 = 8 * i + (lane >> 3), kk = (lane & 7) * 4;
        const bf16x4 pv4 = *(const bf16x4*)&Ptb[q2 * 40 + kk];
        f32x4 v4;
#pragma unroll
        for (int r = 0; r < 4; r++) v4[r] = (float)pv4[r];
        __builtin_nontemporal_store(v4,
            (f32x4*)(wbase + (size_t)q2 * Sc + st * 64 + tl * 32 + kk));
      }
      // PV: A-frag = direct bf16x8 read of own row; B-frag from swizzled sV
#pragma unroll
      for (int stq = 0; stq < 2; stq++) {
        const bf16x8 pa = *(const bf16x8*)&Ptb[l31 * 40 + stq * 16 + hi * 8];
#pragma unroll
        for (int nj = 0; nj < 2; nj++) {
          const int d = nj * 32 + l31;
          const int off = ((tl * 32 + stq * 16 + hi * 8) * 2) ^ ((d & 7) << 4);
          const bf16x8 bv = *(const bf16x8*)(sV + d * 128 + off);
          oacc[nj] = __builtin_amdgcn_mfma_f32_32x32x16_bf16(pa, bv, oacc[nj], 0, 0, 0);
        }
      }
    }
    __syncthreads();
  }

  // ==== ctx write, densified through wave-private Ptb (r10-validated)
#pragma unroll
  for (int nj = 0; nj < 2; nj++) {
#pragma unroll
    for (int rg = 0; rg < 16; rg++) {
      const int qq = (rg & 3) + 8 * (rg >> 2) + 4 * hi;
      Ptb[qq * 40 + l31] = (bf16)oacc[nj][rg];
    }
    const int rr = lane >> 1, c0 = (lane & 1) * 16;
    const bf16x8 o0 = *(const bf16x8*)&Ptb[rr * 40 + c0];
    const bf16x8 o1 = *(const bf16x8*)&Ptb[rr * 40 + c0 + 8];
    bf16* cbase = ctx + ((size_t)(b * Sc + q0 + rr)) * Ec + h * Dc + nj * 32 + c0;
    *(bf16x8*)cbase = o0;
    *(bf16x8*)(cbase + 8) = o1;
  }
}

// ---------------------------------------------------------------------------
extern "C" void kernel_launch(void* const* d_in, const int* in_sizes, int n_in,
                              void* d_out, int out_size, void* d_ws, size_t ws_size,
                              hipStream_t stream) {
  const float* q = (const float*)d_in[0];
  const float* k = (const float*)d_in[1];
  const float* v = (const float*)d_in[2];
  const uint8_t* mask = (const uint8_t*)d_in[3];
  const float* Wq = (const float*)d_in[4];
  const float* bq = (const float*)d_in[5];
  const float* Wk = (const float*)d_in[6];
  const float* bk = (const float*)d_in[7];
  const float* Wv = (const float*)d_in[8];
  const float* bv = (const float*)d_in[9];
  const float* Wo = (const float*)d_in[10];
  const float* bo = (const float*)d_in[11];

  // Workspace (bf16 elems): [0,4M) xb.q -> ctx; [4M,8M) xb.k; [8M,12M) xb.v;
  // [12,16M) wT; [16,24M) Qb/Kb (swizzled K); [24,28M) VTb; byte 56MB: mflag.
  bf16* wsb = (bf16*)d_ws;
  bf16* xb = wsb;
  bf16* ctx = wsb;
  bf16* wT = wsb + (size_t)12 * 1024 * 1024;
  bf16* Qb = wsb + (size_t)16 * 1024 * 1024;
  bf16* Kb = wsb + (size_t)20 * 1024 * 1024;
  bf16* VTb = wsb + (size_t)24 * 1024 * 1024;
  int* mflag = (int*)((char*)d_ws + (size_t)56 * 1024 * 1024);

  float* outf = (float*)d_out;
  float* attnw = outf + (size_t)4 * 1024 * 1024;

  hipMemsetAsync(mflag, 0, 8, stream);
  prep_kernel<<<4096, 256, 0, stream>>>(q, k, v, xb, mask, mflag, Wq, Wk, Wv, Wo, wT);
  gemm128_kernel<1><<<dim3(8, 32, 3), 256, 0, stream>>>(xb, wT, bq, bk, bv, Qb, nullptr, VTb);
  attn_kernel<<<512, 256, 0, stream>>>(Qb, Kb, VTb, mask, mflag, attnw, ctx);
  gemm128_kernel<0><<<dim3(8, 32, 1), 256, 0, stream>>>(ctx, wT + (size_t)3 * 1024 * 1024,
                                                        bo, bo, bo, nullptr, outf, nullptr);
}